// Round 10
// baseline (5123.923 us; speedup 1.0000x reference)
//
#include <hip/hip_runtime.h>

#define BATCH 256
#define SEQ   1024
#define HID   256
#define NU    4      // unit-slices (sibling blocks per batch-group)
#define UNITS 64     // hidden units per block (NU*UNITS == HID)
#define BB    4      // batch elements per block
#define NBG   64     // batch groups (NBG*BB == BATCH)
#define NKG   8      // k-groups inside a block (512 threads = NKG*UNITS)
#define KPG   32     // k columns per k-group (NKG*KPG == HID)
#define LROWS 14     // k-columns per kg resident in LDS
#define SROWS 18     // k-columns per kg streamed from L2 each step (LROWS+SROWS==KPG)

typedef float f32x4 __attribute__((ext_vector_type(4)));

// ---------- fast activations (fp32, ~2 ulp) ----------
__device__ __forceinline__ float tanh_fast(float x) {
    float e = __expf(2.0f * x);
    return 1.0f - 2.0f / (e + 1.0f);
}
__device__ __forceinline__ float sigmoid_fast(float x) {
    return 1.0f / (1.0f + __expf(-x));
}

// ---------- MLP ----------
template<int DIN, int DOUT, bool ACT>
__device__ __forceinline__ void dense(const float* __restrict__ w,
                                      const float* __restrict__ b,
                                      const float* hin, float* hout) {
    #pragma unroll
    for (int i = 0; i < DOUT; i++) {
        float a = b[i];
        #pragma unroll
        for (int j = 0; j < DIN; j++) a = fmaf(w[i * DIN + j], hin[j], a);
        hout[i] = ACT ? tanh_fast(a) : a;
    }
}

__global__ __launch_bounds__(256) void mlp_kernel(
    const float* __restrict__ x,
    const float* __restrict__ w1, const float* __restrict__ b1,
    const float* __restrict__ w2, const float* __restrict__ b2,
    const float* __restrict__ w3, const float* __restrict__ b3,
    const float* __restrict__ w4, const float* __restrict__ b4,
    const float* __restrict__ w5, const float* __restrict__ b5,
    const float* __restrict__ w6, const float* __restrict__ b6,
    const float* __restrict__ w7, const float* __restrict__ b7,
    float* __restrict__ cnn_out)
{
    int n = blockIdx.x * 256 + threadIdx.x;          // n = b*SEQ + s
    float h0[1] = { x[n] };
    float h1[16], h2[16], h3[12], h4[8], h5[4], h6[4], h7[1];
    dense<1, 16, true >(w1, b1, h0, h1);
    dense<16, 16, true >(w2, b2, h1, h2);
    dense<16, 12, true >(w3, b3, h2, h3);
    dense<12, 8, true >(w4, b4, h3, h4);
    dense<8, 4, true >(w5, b5, h4, h5);
    dense<4, 4, true >(w6, b6, h5, h6);
    dense<4, 1, false>(w7, b7, h6, h7);
    cnn_out[n] = h7[0];
}

// ---------- weight pack: wpack[k][j] = (wf, wi, wg, wo)[j][k], k=0..256 ----------
__global__ __launch_bounds__(256) void pack_kernel(
    const float* __restrict__ wf, const float* __restrict__ wi,
    const float* __restrict__ wg, const float* __restrict__ wo,
    f32x4* __restrict__ wpack)
{
    int j = threadIdx.x;
    int k = blockIdx.x;                              // 257 blocks
    int src = j * 257 + k;
    f32x4 v = { wf[src], wi[src], wg[src], wo[src] };
    wpack[k * 256 + j] = v;
}

#define GFMA(A, W, HV)                       \
    (A)[0] = fmaf((W)[0], (HV), (A)[0]);     \
    (A)[1] = fmaf((W)[1], (HV), (A)[1]);     \
    (A)[2] = fmaf((W)[2], (HV), (A)[2]);     \
    (A)[3] = fmaf((W)[3], (HV), (A)[3]);

// ---------- LSTM ----------
// Grid 256 = NU(4) unit-slices x NBG(64) batch-groups (cooperative, 1 block/CU).
// Block: 512 threads = NKG(8) k-groups (kg = wave id, wave-uniform) x UNITS(64).
// R5-R9 lesson: register residency for the 32-f32x4 weight slice is
// unobtainable (allocator remats/spills regardless of launch_bounds,
// waves_per_eu, PIN, volatile asm). This version puts 14/32 k-columns in
// LDS (explicit residency, 114.7 KB) and streams the remaining 18 from L2
// per step via short-lived register loads (allocator-friendly live ranges;
// L2 stream 263->147 KB/step/block ~= 1.1 us on the 4.3 TB/s-per-XCD wall).
// h-reads are wave-uniform broadcasts; wlds reads are conflict-free.
// Cross-block h-exchange: tagged 8B RELAXED SYSTEM-scope atomics (no fences,
// no cache maintenance), parity double-buffered (proven R5-R9).
__global__
__attribute__((amdgpu_waves_per_eu(2, 2)))
__launch_bounds__(512) void lstm_kernel(
    const float* __restrict__ xB,                    // [BATCH][SEQ] cnn features
    const f32x4* __restrict__ wpack,                 // [257][256] (f,i,g,o)
    const float* __restrict__ bf, const float* __restrict__ bi,
    const float* __restrict__ bg_, const float* __restrict__ bo,
    const float* __restrict__ w_head, const float* __restrict__ b_head,
    float* __restrict__ logits,
    unsigned long long* __restrict__ hglob)          // [2][256 blocks][256] u64
{
    __shared__ f32x4 wlds[NKG][LROWS][UNITS];        // 114,688 B
    __shared__ f32x4 partial[NKG][BB][UNITS];        // 32 KB
    __shared__ __align__(16) float hx_s[BB][HID];    // 4 KB   (total 151.5 KB)

    const int bid = blockIdx.x;
    const int u   = bid >> 6;                        // 0..3 unit-slice
    const int bgp = bid & 63;                        // 0..63 batch-group
    const int tid = threadIdx.x;
    const int kg  = tid >> 6;                        // 0..7 (== wave id)
    const int j   = tid & 63;                        // 0..63
    const int unit = u * UNITS + j;

    // stage LDS-resident weight rows: k = 1+kg*32+i, i in [0,LROWS)
    #pragma unroll
    for (int i = 0; i < LROWS; ++i)
        wlds[kg][i][j] = wpack[(1 + kg * KPG + i) * HID + unit];

    const f32x4* wstream = wpack + (size_t)(1 + kg * KPG + LROWS) * HID + unit;
    const f32x4 w0   = wpack[unit];                  // k=0 (x) column
    const f32x4 bias = { bf[unit], bi[unit], bg_[unit], bo[unit] };

    ((float*)hx_s)[tid] = 0.0f;
    ((float*)hx_s)[tid + 512] = 0.0f;

    float cx = 0.0f, hj = 0.0f;
    const int b2 = tid >> 6;                         // phase-2 batch (tid<256)
    const int xrow = (bgp * BB + (tid >> 6)) * SEQ;  // valid for tid<256 only
    __syncthreads();

    for (int t = 0; t < SEQ; ++t) {
        // x for phase-2, issued early so phase-1 hides the L2 latency
        float xt = 0.0f;
        if (tid < 256) xt = xB[xrow + t];

        // streamed weight columns (k = 1+kg*32+LROWS+s) — short-lived regs
        f32x4 wst[SROWS];
        #pragma unroll
        for (int s = 0; s < SROWS; ++s) wst[s] = wstream[(size_t)s * HID];

        // ---- phase 1: partial gate sums ----
        f32x4 acc[BB];
        #pragma unroll
        for (int bb = 0; bb < BB; ++bb) acc[bb] = (f32x4){0.f, 0.f, 0.f, 0.f};

        const f32x4* h0p = (const f32x4*)&hx_s[0][kg * KPG];
        const f32x4* h1p = (const f32x4*)&hx_s[1][kg * KPG];
        const f32x4* h2p = (const f32x4*)&hx_s[2][kg * KPG];
        const f32x4* h3p = (const f32x4*)&hx_s[3][kg * KPG];

        #pragma unroll
        for (int q = 0; q < KPG / 4; ++q) {
            f32x4 ha = h0p[q], hb = h1p[q], hc = h2p[q], hd = h3p[q];
            #pragma unroll
            for (int e = 0; e < 4; ++e) {
                const int k = q * 4 + e;
                f32x4 w = (k < LROWS) ? wlds[kg][k][j] : wst[k - LROWS];
                GFMA(acc[0], w, ha[e]);
                GFMA(acc[1], w, hb[e]);
                GFMA(acc[2], w, hc[e]);
                GFMA(acc[3], w, hd[e]);
            }
        }
        #pragma unroll
        for (int bb = 0; bb < BB; ++bb) partial[kg][bb][j] = acc[bb];
        __syncthreads();

        // ---- phase 2: reduce + activations + state (tid<256: (b2, j)) ----
        float hnew = 0.0f;
        if (tid < 256) {
            f32x4 a = partial[0][b2][j];
            #pragma unroll
            for (int g = 1; g < NKG; ++g) {
                f32x4 p = partial[g][b2][j];
                a[0] += p[0]; a[1] += p[1]; a[2] += p[2]; a[3] += p[3];
            }
            float pf = fmaf(w0[0], xt, a[0] + bias[0]);
            float pi = fmaf(w0[1], xt, a[1] + bias[1]);
            float pg = fmaf(w0[2], xt, a[2] + bias[2]);
            float po = fmaf(w0[3], xt, a[3] + bias[3]);
            float f  = sigmoid_fast(pf);
            float i  = sigmoid_fast(pi);
            float g  = tanh_fast(pg);
            float o  = sigmoid_fast(po);
            cx = fmaf(f, cx, i * g);
            hnew = o * tanh_fast(cx);
            hj = hnew;
        }

        if (t < SEQ - 1) {
            const int par = t & 1;
            // ---- publish own slice: tagged 8B fine-grained store ----
            if (tid < 256) {
                unsigned long long pk =
                    ((unsigned long long)(unsigned)(t + 1) << 32) |
                    (unsigned long long)__float_as_uint(hnew);
                __hip_atomic_store(&hglob[(size_t)par * (256 * 256) + bid * 256 + tid],
                                   pk, __ATOMIC_RELAXED, __HIP_MEMORY_SCOPE_SYSTEM);
                hx_s[b2][u * UNITS + j] = hnew;      // own slice direct to LDS
            }
            asm volatile("" ::: "memory");           // pin store before polls
            // ---- poll the 3 sibling slices (768 slots over 512 threads) ----
            for (int r = tid; r < 768; r += 512) {
                const int s  = r >> 8;               // 0..2
                const int su = (u + 1 + s) & 3;
                const int rr = r & 255;              // (b', j') = (rr>>6, rr&63)
                const unsigned long long* p =
                    hglob + (size_t)par * (256 * 256) + (su * NBG + bgp) * 256 + rr;
                unsigned long long v;
                do {
                    v = __hip_atomic_load(p, __ATOMIC_RELAXED,
                                          __HIP_MEMORY_SCOPE_SYSTEM);
                } while ((int)(v >> 32) != t + 1);
                hx_s[rr >> 6][su * UNITS + (rr & 63)] =
                    __uint_as_float((unsigned)(v & 0xffffffffull));
            }
            __syncthreads();                         // hx complete for next step
        } else {
            if (tid < 256) hx_s[b2][u * UNITS + j] = hnew;
        }
    }

    // ---- head: logits[b] = sum_j w_head[j]*h[j] + b_head (4 partial blocks) ----
    __syncthreads();                                 // reuse partial[] as scratch
    float* red = (float*)partial;
    if (tid < 256) red[tid] = w_head[unit] * hj;
    __syncthreads();
    #pragma unroll
    for (int off = 32; off > 0; off >>= 1) {
        if (tid < 256 && (tid & 63) < off) red[tid] += red[tid + off];
        __syncthreads();
    }
    if (tid < 256 && (tid & 63) == 0) {
        float sum = red[tid] + (u == 0 ? b_head[0] : 0.0f);
        atomicAdd(&logits[bgp * BB + (tid >> 6)], sum);
    }
}

extern "C" void kernel_launch(void* const* d_in, const int* in_sizes, int n_in,
                              void* d_out, int out_size, void* d_ws, size_t ws_size,
                              hipStream_t stream) {
    const float* x      = (const float*)d_in[0];
    const float* w1     = (const float*)d_in[1];
    const float* b1     = (const float*)d_in[2];
    const float* w2     = (const float*)d_in[3];
    const float* b2     = (const float*)d_in[4];
    const float* w3     = (const float*)d_in[5];
    const float* b3     = (const float*)d_in[6];
    const float* w4     = (const float*)d_in[7];
    const float* b4     = (const float*)d_in[8];
    const float* w5     = (const float*)d_in[9];
    const float* b5     = (const float*)d_in[10];
    const float* w6     = (const float*)d_in[11];
    const float* b6     = (const float*)d_in[12];
    const float* w7     = (const float*)d_in[13];
    const float* b7     = (const float*)d_in[14];
    const float* w_f    = (const float*)d_in[15];
    const float* b_f    = (const float*)d_in[16];
    const float* w_i    = (const float*)d_in[17];
    const float* b_i    = (const float*)d_in[18];
    const float* w_g    = (const float*)d_in[19];
    const float* b_g    = (const float*)d_in[20];
    const float* w_o    = (const float*)d_in[21];
    const float* b_o    = (const float*)d_in[22];
    const float* w_head = (const float*)d_in[23];
    const float* b_head = (const float*)d_in[24];

    float* out    = (float*)d_out;                   // [0..262143] cnn_features, then logits
    float* logits = out + BATCH * SEQ;

    char* ws = (char*)d_ws;
    f32x4* wpack = (f32x4*)ws;                       // 1,052,672 B
    unsigned long long* hglob =
        (unsigned long long*)(ws + 1052672);         // 2*256*256*8 = 1,048,576 B

    hipMemsetAsync(hglob, 0, 2 * 256 * 256 * sizeof(unsigned long long), stream);
    hipMemsetAsync(logits, 0, 256 * sizeof(float), stream);
    pack_kernel<<<257, 256, 0, stream>>>(w_f, w_i, w_g, w_o, wpack);
    mlp_kernel<<<(BATCH * SEQ) / 256, 256, 0, stream>>>(
        x, w1, b1, w2, b2, w3, b3, w4, b4, w5, b5, w6, b6, w7, b7, out);

    void* args[] = { (void*)&out, (void*)&wpack,
                     (void*)&b_f, (void*)&b_i, (void*)&b_g, (void*)&b_o,
                     (void*)&w_head, (void*)&b_head,
                     (void*)&logits, (void*)&hglob };
    hipLaunchCooperativeKernel((void*)lstm_kernel, dim3(256), dim3(512),
                               args, 0, stream);
}

// Round 11
// 4789.383 us; speedup vs baseline: 1.0699x; 1.0699x over previous
//
#include <hip/hip_runtime.h>

#define BATCH 256
#define SEQ   1024
#define HID   256
#define NU    4      // unit-slices (sibling blocks per batch-group)
#define UNITS 64     // hidden units per block (NU*UNITS == HID)
#define BB    4      // batch elements per block
#define NBG   64     // batch groups (NBG*BB == BATCH)
#define NKG   8      // k-groups inside a block (512 threads = NKG*UNITS)
#define KPG   32     // k columns per k-group (NKG*KPG == HID)
#define LROWS 12     // k-columns per kg resident in LDS
#define SROWS 20     // k-columns per kg streamed from L2 each step (LROWS+SROWS==KPG)

typedef float f32x4 __attribute__((ext_vector_type(4)));

// ---------- fast activations (fp32, ~2 ulp) ----------
__device__ __forceinline__ float tanh_fast(float x) {
    float e = __expf(2.0f * x);
    return 1.0f - 2.0f / (e + 1.0f);
}
__device__ __forceinline__ float sigmoid_fast(float x) {
    return 1.0f / (1.0f + __expf(-x));
}

// ---------- MLP ----------
template<int DIN, int DOUT, bool ACT>
__device__ __forceinline__ void dense(const float* __restrict__ w,
                                      const float* __restrict__ b,
                                      const float* hin, float* hout) {
    #pragma unroll
    for (int i = 0; i < DOUT; i++) {
        float a = b[i];
        #pragma unroll
        for (int j = 0; j < DIN; j++) a = fmaf(w[i * DIN + j], hin[j], a);
        hout[i] = ACT ? tanh_fast(a) : a;
    }
}

__global__ __launch_bounds__(256) void mlp_kernel(
    const float* __restrict__ x,
    const float* __restrict__ w1, const float* __restrict__ b1,
    const float* __restrict__ w2, const float* __restrict__ b2,
    const float* __restrict__ w3, const float* __restrict__ b3,
    const float* __restrict__ w4, const float* __restrict__ b4,
    const float* __restrict__ w5, const float* __restrict__ b5,
    const float* __restrict__ w6, const float* __restrict__ b6,
    const float* __restrict__ w7, const float* __restrict__ b7,
    float* __restrict__ cnn_out)
{
    int n = blockIdx.x * 256 + threadIdx.x;          // n = b*SEQ + s
    float h0[1] = { x[n] };
    float h1[16], h2[16], h3[12], h4[8], h5[4], h6[4], h7[1];
    dense<1, 16, true >(w1, b1, h0, h1);
    dense<16, 16, true >(w2, b2, h1, h2);
    dense<16, 12, true >(w3, b3, h2, h3);
    dense<12, 8, true >(w4, b4, h3, h4);
    dense<8, 4, true >(w5, b5, h4, h5);
    dense<4, 4, true >(w6, b6, h5, h6);
    dense<4, 1, false>(w7, b7, h6, h7);
    cnn_out[n] = h7[0];
}

// ---------- weight pack: wpack[k][j] = (wf, wi, wg, wo)[j][k], k=0..256 ----------
__global__ __launch_bounds__(256) void pack_kernel(
    const float* __restrict__ wf, const float* __restrict__ wi,
    const float* __restrict__ wg, const float* __restrict__ wo,
    f32x4* __restrict__ wpack)
{
    int j = threadIdx.x;
    int k = blockIdx.x;                              // 257 blocks
    int src = j * 257 + k;
    f32x4 v = { wf[src], wi[src], wg[src], wo[src] };
    wpack[k * 256 + j] = v;
}

#define GFMA(A, W, HV)                       \
    (A)[0] = fmaf((W)[0], (HV), (A)[0]);     \
    (A)[1] = fmaf((W)[1], (HV), (A)[1]);     \
    (A)[2] = fmaf((W)[2], (HV), (A)[2]);     \
    (A)[3] = fmaf((W)[3], (HV), (A)[3]);

// ---------- LSTM ----------
// Grid 256 = NU(4) unit-slices x NBG(64) batch-groups (cooperative, 1 block/CU).
// Block: 512 threads = NKG(8) k-groups (kg = wave id) x UNITS(64).
// Weights: 12/32 k-columns per kg LDS-resident (98 KB, loaded once, 0 bank
// conflicts measured in R10); 20/32 streamed from L2 per step in 4-column
// chunks with loads INSIDE the unrolled loop (R10 failure: issuing all 18
// up-front = 72 live VGPRs -> spill to scratch -> traffic doubled, VGPR
// pegged at 128, dur 5.3ms. Chunked live range ~16 regs -> no spill).
// x staged in xlds once (R10's per-step xt load was 256 uncoalesced lines).
// Cross-block h-exchange: tagged 8B RELAXED SYSTEM-scope atomics (no fences,
// no cache maintenance), parity double-buffered (proven R5-R10).
__global__
__attribute__((amdgpu_waves_per_eu(2, 2)))
__launch_bounds__(512) void lstm_kernel(
    const float* __restrict__ xB,                    // [BATCH][SEQ] cnn features
    const f32x4* __restrict__ wpack,                 // [257][256] (f,i,g,o)
    const float* __restrict__ bf, const float* __restrict__ bi,
    const float* __restrict__ bg_, const float* __restrict__ bo,
    const float* __restrict__ w_head, const float* __restrict__ b_head,
    float* __restrict__ logits,
    unsigned long long* __restrict__ hglob)          // [2][256 blocks][256] u64
{
    __shared__ f32x4 wlds[NKG][LROWS][UNITS];        // 98,304 B
    __shared__ f32x4 partial[NKG][BB][UNITS];        // 32,768 B
    __shared__ __align__(16) float hx_s[BB][HID];    // 4,096 B
    __shared__ float xlds[BB * SEQ];                 // 16,384 B  (total 151,552)

    const int bid = blockIdx.x;
    const int u   = bid >> 6;                        // 0..3 unit-slice
    const int bgp = bid & 63;                        // 0..63 batch-group
    const int tid = threadIdx.x;
    const int kg  = tid >> 6;                        // 0..7 (== wave id)
    const int j   = tid & 63;                        // 0..63
    const int unit = u * UNITS + j;

    // stage LDS-resident weight rows: k = 1+kg*32+i, i in [0,LROWS)
    #pragma unroll
    for (int i = 0; i < LROWS; ++i)
        wlds[kg][i][j] = wpack[(1 + kg * KPG + i) * HID + unit];

    const f32x4* wstream = wpack + (size_t)(1 + kg * KPG + LROWS) * HID + unit;
    const f32x4 w0   = wpack[unit];                  // k=0 (x) column
    const f32x4 bias = { bf[unit], bi[unit], bg_[unit], bo[unit] };

    // stage this group's x: xlds[b'*SEQ + s] (coalesced, once)
    #pragma unroll
    for (int i = 0; i < 8; i++)
        xlds[i * 512 + tid] = xB[(bgp * BB) * SEQ + i * 512 + tid];
    ((float*)hx_s)[tid] = 0.0f;
    ((float*)hx_s)[tid + 512] = 0.0f;

    float cx = 0.0f, hj = 0.0f;
    const int b2 = tid >> 6;                         // phase-2 batch (tid<256)
    __syncthreads();

    for (int t = 0; t < SEQ; ++t) {
        // ---- phase 1: partial gate sums ----
        f32x4 acc[BB];
        #pragma unroll
        for (int bb = 0; bb < BB; ++bb) acc[bb] = (f32x4){0.f, 0.f, 0.f, 0.f};

        const f32x4* h0p = (const f32x4*)&hx_s[0][kg * KPG];
        const f32x4* h1p = (const f32x4*)&hx_s[1][kg * KPG];
        const f32x4* h2p = (const f32x4*)&hx_s[2][kg * KPG];
        const f32x4* h3p = (const f32x4*)&hx_s[3][kg * KPG];

        // LDS-resident columns: k-chunk q = 0..2 (k = 0..11)
        #pragma unroll
        for (int q = 0; q < LROWS / 4; ++q) {
            f32x4 ha = h0p[q], hb = h1p[q], hc = h2p[q], hd = h3p[q];
            #pragma unroll
            for (int e = 0; e < 4; ++e) {
                f32x4 w = wlds[kg][q * 4 + e][j];
                GFMA(acc[0], w, ha[e]);
                GFMA(acc[1], w, hb[e]);
                GFMA(acc[2], w, hc[e]);
                GFMA(acc[3], w, hd[e]);
            }
        }
        // streamed columns: k-chunk q = 3..7 (k = 12..31), loads in-chunk
        #pragma unroll
        for (int q = LROWS / 4; q < KPG / 4; ++q) {
            const int s0 = q * 4 - LROWS;
            f32x4 wa = wstream[(size_t)(s0 + 0) * HID];
            f32x4 wb = wstream[(size_t)(s0 + 1) * HID];
            f32x4 wc = wstream[(size_t)(s0 + 2) * HID];
            f32x4 wd = wstream[(size_t)(s0 + 3) * HID];
            f32x4 ha = h0p[q], hb = h1p[q], hc = h2p[q], hd = h3p[q];
            GFMA(acc[0], wa, ha[0]); GFMA(acc[1], wa, hb[0]);
            GFMA(acc[2], wa, hc[0]); GFMA(acc[3], wa, hd[0]);
            GFMA(acc[0], wb, ha[1]); GFMA(acc[1], wb, hb[1]);
            GFMA(acc[2], wb, hc[1]); GFMA(acc[3], wb, hd[1]);
            GFMA(acc[0], wc, ha[2]); GFMA(acc[1], wc, hb[2]);
            GFMA(acc[2], wc, hc[2]); GFMA(acc[3], wc, hd[2]);
            GFMA(acc[0], wd, ha[3]); GFMA(acc[1], wd, hb[3]);
            GFMA(acc[2], wd, hc[3]); GFMA(acc[3], wd, hd[3]);
        }
        #pragma unroll
        for (int bb = 0; bb < BB; ++bb) partial[kg][bb][j] = acc[bb];
        __syncthreads();

        // ---- phase 2: reduce + activations + state (tid<256: (b2, j)) ----
        float hnew = 0.0f;
        if (tid < 256) {
            f32x4 a = partial[0][b2][j];
            #pragma unroll
            for (int g = 1; g < NKG; ++g) {
                f32x4 p = partial[g][b2][j];
                a[0] += p[0]; a[1] += p[1]; a[2] += p[2]; a[3] += p[3];
            }
            float xt = xlds[b2 * 1024 + t];
            float pf = fmaf(w0[0], xt, a[0] + bias[0]);
            float pi = fmaf(w0[1], xt, a[1] + bias[1]);
            float pg = fmaf(w0[2], xt, a[2] + bias[2]);
            float po = fmaf(w0[3], xt, a[3] + bias[3]);
            float f  = sigmoid_fast(pf);
            float i  = sigmoid_fast(pi);
            float g  = tanh_fast(pg);
            float o  = sigmoid_fast(po);
            cx = fmaf(f, cx, i * g);
            hnew = o * tanh_fast(cx);
            hj = hnew;
        }

        if (t < SEQ - 1) {
            const int par = t & 1;
            // ---- publish own slice: tagged 8B fine-grained store ----
            if (tid < 256) {
                unsigned long long pk =
                    ((unsigned long long)(unsigned)(t + 1) << 32) |
                    (unsigned long long)__float_as_uint(hnew);
                __hip_atomic_store(&hglob[(size_t)par * (256 * 256) + bid * 256 + tid],
                                   pk, __ATOMIC_RELAXED, __HIP_MEMORY_SCOPE_SYSTEM);
                hx_s[b2][u * UNITS + j] = hnew;      // own slice direct to LDS
            }
            asm volatile("" ::: "memory");           // pin store before polls
            // ---- poll the 3 sibling slices (768 slots over 512 threads) ----
            for (int r = tid; r < 768; r += 512) {
                const int s  = r >> 8;               // 0..2
                const int su = (u + 1 + s) & 3;
                const int rr = r & 255;              // (b', j') = (rr>>6, rr&63)
                const unsigned long long* p =
                    hglob + (size_t)par * (256 * 256) + (su * NBG + bgp) * 256 + rr;
                unsigned long long v;
                do {
                    v = __hip_atomic_load(p, __ATOMIC_RELAXED,
                                          __HIP_MEMORY_SCOPE_SYSTEM);
                } while ((int)(v >> 32) != t + 1);
                hx_s[rr >> 6][su * UNITS + (rr & 63)] =
                    __uint_as_float((unsigned)(v & 0xffffffffull));
            }
            __syncthreads();                         // hx complete for next step
        } else {
            if (tid < 256) hx_s[b2][u * UNITS + j] = hnew;
        }
    }

    // ---- head: logits[b] = sum_j w_head[j]*h[j] + b_head (4 partial blocks) ----
    __syncthreads();                                 // reuse partial[] as scratch
    float* red = (float*)partial;
    if (tid < 256) red[tid] = w_head[unit] * hj;
    __syncthreads();
    #pragma unroll
    for (int off = 32; off > 0; off >>= 1) {
        if (tid < 256 && (tid & 63) < off) red[tid] += red[tid + off];
        __syncthreads();
    }
    if (tid < 256 && (tid & 63) == 0) {
        float sum = red[tid] + (u == 0 ? b_head[0] : 0.0f);
        atomicAdd(&logits[bgp * BB + (tid >> 6)], sum);
    }
}

extern "C" void kernel_launch(void* const* d_in, const int* in_sizes, int n_in,
                              void* d_out, int out_size, void* d_ws, size_t ws_size,
                              hipStream_t stream) {
    const float* x      = (const float*)d_in[0];
    const float* w1     = (const float*)d_in[1];
    const float* b1     = (const float*)d_in[2];
    const float* w2     = (const float*)d_in[3];
    const float* b2     = (const float*)d_in[4];
    const float* w3     = (const float*)d_in[5];
    const float* b3     = (const float*)d_in[6];
    const float* w4     = (const float*)d_in[7];
    const float* b4     = (const float*)d_in[8];
    const float* w5     = (const float*)d_in[9];
    const float* b5     = (const float*)d_in[10];
    const float* w6     = (const float*)d_in[11];
    const float* b6     = (const float*)d_in[12];
    const float* w7     = (const float*)d_in[13];
    const float* b7     = (const float*)d_in[14];
    const float* w_f    = (const float*)d_in[15];
    const float* b_f    = (const float*)d_in[16];
    const float* w_i    = (const float*)d_in[17];
    const float* b_i    = (const float*)d_in[18];
    const float* w_g    = (const float*)d_in[19];
    const float* b_g    = (const float*)d_in[20];
    const float* w_o    = (const float*)d_in[21];
    const float* b_o    = (const float*)d_in[22];
    const float* w_head = (const float*)d_in[23];
    const float* b_head = (const float*)d_in[24];

    float* out    = (float*)d_out;                   // [0..262143] cnn_features, then logits
    float* logits = out + BATCH * SEQ;

    char* ws = (char*)d_ws;
    f32x4* wpack = (f32x4*)ws;                       // 1,052,672 B
    unsigned long long* hglob =
        (unsigned long long*)(ws + 1052672);         // 2*256*256*8 = 1,048,576 B

    hipMemsetAsync(hglob, 0, 2 * 256 * 256 * sizeof(unsigned long long), stream);
    hipMemsetAsync(logits, 0, 256 * sizeof(float), stream);
    pack_kernel<<<257, 256, 0, stream>>>(w_f, w_i, w_g, w_o, wpack);
    mlp_kernel<<<(BATCH * SEQ) / 256, 256, 0, stream>>>(
        x, w1, b1, w2, b2, w3, b3, w4, b4, w5, b5, w6, b6, w7, b7, out);

    void* args[] = { (void*)&out, (void*)&wpack,
                     (void*)&b_f, (void*)&b_i, (void*)&b_g, (void*)&b_o,
                     (void*)&w_head, (void*)&b_head,
                     (void*)&logits, (void*)&hglob };
    hipLaunchCooperativeKernel((void*)lstm_kernel, dim3(256), dim3(512),
                               args, 0, stream);
}